// Round 6
// baseline (3236.616 us; speedup 1.0000x reference)
//
#include <hip/hip_runtime.h>

typedef unsigned short u16;
typedef unsigned int u32;
typedef __bf16 bf16x8 __attribute__((ext_vector_type(8)));
typedef float f32x4 __attribute__((ext_vector_type(4)));

#define LAYERS 6
#define NH 16
#define CDIM 1024
#define HS 64
#define FFDIM 4096
#define VOCAB 67
#define BATCH 8
#define TSEQ 1024
#define NTOK (BATCH * TSEQ)

__device__ __forceinline__ float bf2f(u16 u) {
    union { u32 i; float f; } x; x.i = ((u32)u) << 16; return x.f;
}
__device__ __forceinline__ u16 f2bf(float f) {  // round-to-nearest-even
    u32 x = __float_as_uint(f);
    u32 r = (x + 0x7fffu + ((x >> 16) & 1u)) >> 16;
    return (u16)r;
}
// dtype-flexible external-input load: f32 ? fp32[i] : bf16[i]
__device__ __forceinline__ float ldx(const void* p, size_t i, int f32) {
    return f32 ? ((const float*)p)[i] : bf2f(((const u16*)p)[i]);
}
// async global->LDS, 16 B per lane; lds base must be wave-uniform (HW scatters +lane*16)
__device__ __forceinline__ void glds16(const u16* g, u16* lds) {
    __builtin_amdgcn_global_load_lds(
        (const __attribute__((address_space(1))) void*)g,
        (__attribute__((address_space(3))) void*)lds, 16, 0, 0);
}

// ---------------------------------------------------------------- dtype detector
__global__ void detect_kernel(const void* __restrict__ tok, int* __restrict__ flag) {
    int bad = 0;
    for (int i = threadIdx.x; i < 4096; i += 256) {
        float f = bf2f(((const u16*)tok)[i]);
        if (!(fabsf(f) < 1000.0f)) bad = 1;   // catches NaN too (comparison false)
    }
    if (bad) atomicOr(flag, 1);
}

// ---------------------------------------------------------------- embedding
template <int BF16OUT>
__global__ void embed_kernel(const int* __restrict__ idx, const void* __restrict__ tok,
                             const void* __restrict__ pos, void* __restrict__ X,
                             const int* __restrict__ dflag) {
    const int f32 = *dflag;
    const int i = blockIdx.x * 256 + threadIdx.x;          // over NTOK*CDIM
    const int n = i >> 10, cc = i & 1023;
    const int t = n & 1023;
    const float v = ldx(tok, (size_t)idx[n] * CDIM + cc, f32) + ldx(pos, (size_t)t * CDIM + cc, f32);
    if constexpr (BF16OUT) ((u16*)X)[i] = f2bf(v);
    else                   ((float*)X)[i] = v;
}

// ---------------------------------------------------------------- transpose
// src rows r (0..R-1) with row stride SC at column offset inside soff; C cols moved.
// dst[c*R + r] (bf16). BF16SRC=1 forces bf16 source (internal buffers).
template <int BF16SRC>
__global__ void transpose_kernel(const void* __restrict__ src, size_t soff, u16* __restrict__ dst,
                                 int R, int C, int SC, const int* __restrict__ dflag) {
    __shared__ u16 tile[32][33];
    const int f32 = BF16SRC ? 0 : *dflag;
    const int bx = blockIdx.x * 32, by = blockIdx.y * 32;
    const int tx = threadIdx.x, ty = threadIdx.y;          // block (32,8)
    #pragma unroll
    for (int i = 0; i < 32; i += 8) {
        const size_t si = soff + (size_t)(by + ty + i) * SC + bx + tx;
        tile[ty + i][tx] = f32 ? f2bf(((const float*)src)[si]) : ((const u16*)src)[si];
    }
    __syncthreads();
    #pragma unroll
    for (int i = 0; i < 32; i += 8) dst[(size_t)(bx + ty + i) * R + by + tx] = tile[tx][ty + i];
}

// ---------------------------------------------------------------- layernorm (two-pass), fp32 or bf16 input row
template <int BF16IN>
__global__ __launch_bounds__(256) void ln_kernel(const void* __restrict__ Xv, const void* __restrict__ g,
                                                 const void* __restrict__ b, size_t loff,
                                                 u16* __restrict__ Hout, const int* __restrict__ dflag) {
    __shared__ float sred[4];
    const int f32 = *dflag;
    const int row = blockIdx.x, tid = threadIdx.x;
    float v[4];
    if constexpr (BF16IN) {
        const u16* xr = (const u16*)Xv + (size_t)row * CDIM;
        #pragma unroll
        for (int i = 0; i < 4; ++i) v[i] = bf2f(xr[tid + i * 256]);
    } else {
        const float* xr = (const float*)Xv + (size_t)row * CDIM;
        #pragma unroll
        for (int i = 0; i < 4; ++i) v[i] = xr[tid + i * 256];
    }
    float s = v[0] + v[1] + v[2] + v[3];
    #pragma unroll
    for (int off = 1; off < 64; off <<= 1) s += __shfl_xor(s, off, 64);
    if ((tid & 63) == 0) sred[tid >> 6] = s;
    __syncthreads();
    const float mean = (sred[0] + sred[1] + sred[2] + sred[3]) * (1.f / 1024.f);
    __syncthreads();
    float sq = 0.f;
    #pragma unroll
    for (int i = 0; i < 4; ++i) { v[i] -= mean; sq += v[i] * v[i]; }
    #pragma unroll
    for (int off = 1; off < 64; off <<= 1) sq += __shfl_xor(sq, off, 64);
    if ((tid & 63) == 0) sred[tid >> 6] = sq;
    __syncthreads();
    const float var = (sred[0] + sred[1] + sred[2] + sred[3]) * (1.f / 1024.f);
    const float inv = rsqrtf(var + 1e-5f);
    u16* hr = Hout + (size_t)row * CDIM;
    #pragma unroll
    for (int i = 0; i < 4; ++i) {
        const int cc = tid + i * 256;
        hr[cc] = f2bf(v[i] * inv * ldx(g, loff + cc, f32) + ldx(b, loff + cc, f32));
    }
}

// ---------------------------------------------------------------- GEMM  C[M,N] = A[M,K] @ BT[N,K]^T
// MODE 0: Out=bf16(acc);  MODE 1: Out=bf16(relu(acc+bias));
// MODE 2: X(fp32) += acc+bias;  MODE 3: Out(bf16) = bf16(bf2f(Out)+acc+bias)
// global_load_lds staging with XOR-swizzled LDS (linear dest + inverse-permuted
// source + permuted read). XCD strip mapping, bx-inner for A-panel L2 reuse.
template <int MODE>
__global__ __launch_bounds__(256) void gemm_bt(const u16* __restrict__ A, const u16* __restrict__ BT,
                                               const void* __restrict__ bias, size_t boff,
                                               float* __restrict__ X, u16* __restrict__ Out,
                                               int M, int N, int K, const int* __restrict__ dflag) {
    __shared__ u16 As[128][64];
    __shared__ u16 Bs[128][64];
    const int tid = threadIdx.x;
    const int lane = tid & 63;
    const int w = tid >> 6;
    const int wr = w >> 1, wc = w & 1;
    const int quad = lane >> 4, c = lane & 15;

    const int gx = gridDim.x, gy = gridDim.y;
    int bx = blockIdx.x, by = blockIdx.y;
    const int nwg = gx * gy;
    if ((nwg & 7) == 0) {
        const int bid = by * gx + bx;
        const int q = nwg >> 3;
        const int xcd = bid & 7;
        const int u = bid >> 3;             // local index within this XCD's strip
        const int cols = q / gy;
        if (cols * gy == q) {               // exact strip: cols consecutive bx columns
            bx = xcd * cols + (u % cols);   // bx-inner: A-panel (by) reused across cols
            by = u / cols;
        } else {                            // fallback: contiguous column-major strip
            const int l = xcd * q + u;
            bx = l / gy;
            by = l - bx * gy;
        }
    }
    const int m0 = by * 128, n0 = bx * 128;

    const int lr = lane >> 3;              // row-within-8 per lane
    const int sc = ((lane & 7) ^ lr) * 8;  // inverse-swizzled source chunk (u16 units)

    const f32x4 zero4 = {0.f, 0.f, 0.f, 0.f};
    f32x4 acc[4][4];
    #pragma unroll
    for (int i = 0; i < 4; ++i)
        #pragma unroll
        for (int j = 0; j < 4; ++j) acc[i][j] = zero4;

    for (int k0 = 0; k0 < K; k0 += 64) {
        #pragma unroll
        for (int i = 0; i < 4; ++i) {
            const int rbase = w * 8 + i * 32;   // wave-uniform LDS row base (mult of 8)
            glds16(A  + (size_t)(m0 + rbase + lr) * K + k0 + sc, &As[rbase][0]);
            glds16(BT + (size_t)(n0 + rbase + lr) * K + k0 + sc, &Bs[rbase][0]);
        }
        __syncthreads();   // compiler drains vmcnt(0) before s_barrier
        #pragma unroll
        for (int ks = 0; ks < 2; ++ks) {
            bf16x8 af[4], bfr[4];
            #pragma unroll
            for (int t = 0; t < 4; ++t) {
                const int ch = ((ks * 4 + quad) ^ (c & 7)) * 8;   // swizzled read chunk
                af[t]  = *(const bf16x8*)(&As[wr * 64 + t * 16 + c][ch]);
                bfr[t] = *(const bf16x8*)(&Bs[wc * 64 + t * 16 + c][ch]);
            }
            #pragma unroll
            for (int mt = 0; mt < 4; ++mt)
                #pragma unroll
                for (int nt = 0; nt < 4; ++nt)
                    acc[mt][nt] = __builtin_amdgcn_mfma_f32_16x16x32_bf16(af[mt], bfr[nt], acc[mt][nt], 0, 0, 0);
        }
        __syncthreads();
    }

    int f32 = 0;
    if constexpr (MODE >= 1) f32 = *dflag;
    #pragma unroll
    for (int mt = 0; mt < 4; ++mt) {
        #pragma unroll
        for (int nt = 0; nt < 4; ++nt) {
            const int col = n0 + wc * 64 + nt * 16 + c;
            float bv = 0.f;
            if constexpr (MODE >= 1) bv = ldx(bias, boff + col, f32);
            #pragma unroll
            for (int r = 0; r < 4; ++r) {
                const size_t row = (size_t)(m0 + wr * 64 + mt * 16 + quad * 4 + r);
                float v = acc[mt][nt][r];
                if constexpr (MODE == 2) {
                    X[row * N + col] += v + bv;
                } else if constexpr (MODE == 3) {
                    u16* o = &Out[row * N + col];
                    *o = f2bf(bf2f(*o) + v + bv);
                } else if constexpr (MODE == 1) {
                    v += bv; v = fmaxf(v, 0.f);
                    Out[row * N + col] = f2bf(v);
                } else {
                    Out[row * N + col] = f2bf(v);
                }
            }
        }
    }
}

// ---------------------------------------------------------------- flash attention v2 (causal, H=16, HS=64)
// No K/V/Q LDS staging: Q/K fragments read direct from global (L2-hot); V read from
// pre-transposed VT[CDIM][tokens]. Only P round-trips LDS (per-wave tile, swizzled,
// no barriers). rs = Q/K row stride (3072 fused); vstride = tokens in VT row.
// Block remap: each XCD owns 1/8 of (b,h); longest q-blocks dispatch first.
__global__ __launch_bounds__(256) void attn_kernel(const u16* __restrict__ Qb, const u16* __restrict__ Kb,
                                                   const u16* __restrict__ VT, u16* __restrict__ Ob,
                                                   int rs, int vstride) {
    __shared__ u16 Ps[4][16][64];    // per-wave P tile (q x k), XOR-swizzled

    const int tid = threadIdx.x;
    const int lane = tid & 63;
    const int w = tid >> 6;
    const int quad = lane >> 4;
    const int c = lane & 15;

    const int nbh = gridDim.x, nq = gridDim.y;
    int bh, qi;
    {
        const int flat = blockIdx.y * nbh + blockIdx.x;
        if ((nbh & 7) == 0) {
            const int bpx = nbh >> 3;           // bh per XCD
            const int xcd = flat & 7;
            const int u = flat >> 3;
            bh = xcd * bpx + (u % bpx);
            qi = nq - 1 - u / bpx;              // longest-first
        } else { bh = blockIdx.x; qi = blockIdx.y; }
    }
    const int b = bh >> 4;
    const int h = bh & 15;
    const int q0 = qi * 64;
    const size_t base = ((size_t)b * TSEQ) * rs + (size_t)h * HS;

    const int qbase = q0 + w * 16;
    const u16* qrow = Qb + base + (size_t)(qbase + c) * rs;
    const bf16x8 qf0 = *(const bf16x8*)(qrow + quad * 8);
    const bf16x8 qf1 = *(const bf16x8*)(qrow + 32 + quad * 8);

    const u16* krow = Kb + base + (size_t)c * rs + quad * 8;
    const u16* vrow = VT + (size_t)(h * HS) * vstride + (size_t)b * TSEQ;

    const f32x4 zero4 = {0.f, 0.f, 0.f, 0.f};
    f32x4 oacc[4] = {zero4, zero4, zero4, zero4};
    float m_r[4], l_r[4];
    #pragma unroll
    for (int r = 0; r < 4; ++r) { m_r[r] = -1e30f; l_r[r] = 0.f; }

    const int nch = qi + 1;   // causal: keys up to q0+63
    for (int ch = 0; ch < nch; ++ch) {
        const int k0 = ch * 64;
        f32x4 s[4];
        #pragma unroll
        for (int kt = 0; kt < 4; ++kt) {
            const u16* kp = krow + (size_t)(k0 + kt * 16) * rs;
            const bf16x8 kf0 = *(const bf16x8*)(kp);
            const bf16x8 kf1 = *(const bf16x8*)(kp + 32);
            f32x4 t0 = __builtin_amdgcn_mfma_f32_16x16x32_bf16(qf0, kf0, zero4, 0, 0, 0);
            s[kt] = __builtin_amdgcn_mfma_f32_16x16x32_bf16(qf1, kf1, t0, 0, 0, 0);
        }
        #pragma unroll
        for (int kt = 0; kt < 4; ++kt) {
            const int kabs = k0 + kt * 16 + c;
            #pragma unroll
            for (int r = 0; r < 4; ++r) {
                s[kt][r] *= 0.125f;    // 1/sqrt(HS), exact
                if (kabs > qbase + quad * 4 + r) s[kt][r] = -1e30f;
            }
        }
        float p[4][4];
        #pragma unroll
        for (int r = 0; r < 4; ++r) {
            float rm = fmaxf(fmaxf(s[0][r], s[1][r]), fmaxf(s[2][r], s[3][r]));
            #pragma unroll
            for (int off = 1; off < 16; off <<= 1) rm = fmaxf(rm, __shfl_xor(rm, off, 16));
            const float mnew = fmaxf(m_r[r], rm);
            const float alpha = __expf(m_r[r] - mnew);
            float psum = 0.f;
            #pragma unroll
            for (int kt = 0; kt < 4; ++kt) {
                const float e = __expf(s[kt][r] - mnew);
                p[kt][r] = e; psum += e;
            }
            #pragma unroll
            for (int off = 1; off < 16; off <<= 1) psum += __shfl_xor(psum, off, 16);
            l_r[r] = l_r[r] * alpha + psum;
            m_r[r] = mnew;
            #pragma unroll
            for (int dt = 0; dt < 4; ++dt) oacc[dt][r] *= alpha;
        }
        // write P swizzled: LDS chunk = (G-chunk) ^ (row&7); per-wave tile -> no barrier
        #pragma unroll
        for (int kt = 0; kt < 4; ++kt)
            #pragma unroll
            for (int r = 0; r < 4; ++r) {
                const int prow = quad * 4 + r;
                const int ch2 = (kt * 2 + (c >> 3)) ^ (prow & 7);
                Ps[w][prow][ch2 * 8 + (c & 7)] = f2bf(p[kt][r]);
            }
        #pragma unroll
        for (int ks2 = 0; ks2 < 2; ++ks2) {
            const bf16x8 pf = *(const bf16x8*)(&Ps[w][c][(((ks2 * 4 + quad) ^ (c & 7))) * 8]);
            #pragma unroll
            for (int dt = 0; dt < 4; ++dt) {
                const u16* vp = vrow + (size_t)(dt * 16 + c) * vstride + k0 + ks2 * 32 + quad * 8;
                const bf16x8 vf = *(const bf16x8*)(vp);
                oacc[dt] = __builtin_amdgcn_mfma_f32_16x16x32_bf16(pf, vf, oacc[dt], 0, 0, 0);
            }
        }
    }
    #pragma unroll
    for (int dt = 0; dt < 4; ++dt)
        #pragma unroll
        for (int r = 0; r < 4; ++r) {
            const size_t row = (size_t)b * TSEQ + qbase + quad * 4 + r;
            Ob[row * CDIM + h * HS + dt * 16 + c] = f2bf(oacc[dt][r] / l_r[r]);
        }
}

// ---------------------------------------------------------------- Wlm transpose: Wlm[C,V] -> WlmT[V][C] bf16
__global__ void wlmT_kernel(const void* __restrict__ Wlm, u16* __restrict__ WlmT,
                            const int* __restrict__ dflag) {
    const int f32 = *dflag;
    const int i = blockIdx.x * 256 + threadIdx.x;   // over VOCAB*CDIM
    if (i >= VOCAB * CDIM) return;
    const int v = i >> 10, cc = i & 1023;
    WlmT[i] = f2bf(ldx(Wlm, (size_t)cc * VOCAB + v, f32));
}

// ---------------------------------------------------------------- LM head v2: one wave per token row
__device__ __forceinline__ void ld16bf(const u16* p, float* v) {
    const uint4 a = *(const uint4*)(p);
    const uint4 b = *(const uint4*)(p + 8);
    u32 t[8] = {a.x, a.y, a.z, a.w, b.x, b.y, b.z, b.w};
    #pragma unroll
    for (int i = 0; i < 8; ++i) {
        v[2 * i]     = bf2f((u16)(t[i] & 0xffffu));
        v[2 * i + 1] = bf2f((u16)(t[i] >> 16));
    }
}

__global__ __launch_bounds__(256) void lmhead2_kernel(const u16* __restrict__ Hf, const u16* __restrict__ WlmT,
                                                      const void* __restrict__ blm, void* __restrict__ out,
                                                      size_t ooff, const int* __restrict__ dflag) {
    const int f32 = *dflag;
    const int lane = threadIdx.x & 63;
    const int n = blockIdx.x * 4 + (threadIdx.x >> 6);     // 4 waves per block, 1 row per wave
    float hv[16];
    ld16bf(Hf + (size_t)n * CDIM + lane * 16, hv);
    for (int v = 0; v < VOCAB; ++v) {
        float wv[16];
        ld16bf(WlmT + (size_t)v * CDIM + lane * 16, wv);
        float s = 0.f;
        #pragma unroll
        for (int i = 0; i < 16; ++i) s += hv[i] * wv[i];
        #pragma unroll
        for (int off = 1; off < 64; off <<= 1) s += __shfl_xor(s, off, 64);
        if (lane == 0) {
            s += ldx(blm, v, f32);
            const size_t o = ooff + (size_t)n * VOCAB + v;
            if (f32) ((float*)out)[o] = s;
            else     ((u16*)out)[o]   = f2bf(s);
        }
    }
}

// ---------------------------------------------------------------- launcher
extern "C" void kernel_launch(void* const* d_in, const int* in_sizes, int n_in,
                              void* d_out, int out_size, void* d_ws, size_t ws_size,
                              hipStream_t stream) {
    const int*  idx  = (const int*)d_in[0];
    const void* tok  = d_in[1];
    const void* pos  = d_in[2];
    const void* Wq   = d_in[3];
    const void* Wk   = d_in[4];
    const void* Wv   = d_in[5];
    const void* Wo   = d_in[6];
    const void* bo   = d_in[7];
    const void* ln1g = d_in[8];
    const void* ln1b = d_in[9];
    const void* ln2g = d_in[10];
    const void* ln2b = d_in[11];
    const void* W1   = d_in[12];
    const void* b1   = d_in[13];
    const void* W2   = d_in[14];
    const void* b2   = d_in[15];
    const void* lnfg = d_in[16];
    const void* lnfb = d_in[17];
    const void* Wlm  = d_in[18];
    const void* blm  = d_in[19];

    const dim3 tb(32, 8);
    const size_t wsz = (size_t)CDIM * CDIM;
    const size_t MB = 1048576ull;

    int* dflag = (int*)d_ws;                    // flag at ws[0..4); pool after 256 B
    char* pool = (char*)d_ws + 256;
    const size_t pool_size = (ws_size > 256) ? ws_size - 256 : 0;

    const int wlmT_blocks = (VOCAB * CDIM + 255) / 256;

    if (pool_size >= 120 * MB) {
        // ---------------- Tier A: full-size activations, fp32 residual ----------------
        hipMemsetAsync(d_ws, 0, 256 + 120 * MB, stream);   // defensive full-pool zero
        detect_kernel<<<1, 256, 0, stream>>>(tok, dflag);
        char* p = pool;
        u16* wT = (u16*)p;  p += (size_t)FFDIM * CDIM * 2;   // 8 MB
        u16* WqT = wT;
        u16* WkT = wT + 1 * wsz;
        u16* WvT = wT + 2 * wsz;
        u16* WoT = wT + 3 * wsz;
        float* x = (float*)p; p += (size_t)NTOK * CDIM * 4;  // 32 MB
        u16* h   = (u16*)p;   p += (size_t)NTOK * CDIM * 2;  // 16 MB (also VT during attn)
        u16* qb  = (u16*)p;   p += (size_t)NTOK * CDIM * 2;  // qb..vb = fused QKV [NTOK][3072]
        u16* kb  = (u16*)p;   p += (size_t)NTOK * CDIM * 2;  (void)kb;
        u16* vb  = (u16*)p;   p += (size_t)NTOK * CDIM * 2;  (void)vb;
        u16* ob  = (u16*)p;   p += (size_t)NTOK * CDIM * 2;
        u16* ffh = qb;

        embed_kernel<0><<<NTOK * CDIM / 256, 256, 0, stream>>>(idx, tok, pos, x, dflag);
        for (int l = 0; l < LAYERS; ++l) {
            transpose_kernel<0><<<dim3(32, 32), tb, 0, stream>>>(Wq, l * wsz, WqT, CDIM, CDIM, CDIM, dflag);
            transpose_kernel<0><<<dim3(32, 32), tb, 0, stream>>>(Wk, l * wsz, WkT, CDIM, CDIM, CDIM, dflag);
            transpose_kernel<0><<<dim3(32, 32), tb, 0, stream>>>(Wv, l * wsz, WvT, CDIM, CDIM, CDIM, dflag);
            transpose_kernel<0><<<dim3(32, 32), tb, 0, stream>>>(Wo, l * wsz, WoT, CDIM, CDIM, CDIM, dflag);
            ln_kernel<0><<<NTOK, 256, 0, stream>>>(x, ln1g, ln1b, (size_t)l * CDIM, h, dflag);
            // fused QKV: BT = stacked [WqT;WkT;WvT], out row stride 3072
            gemm_bt<0><<<dim3(24, 64), 256, 0, stream>>>(h, wT, nullptr, 0, nullptr, qb, NTOK, 3 * CDIM, CDIM, dflag);
            // V columns of fused buffer -> VT[CDIM][NTOK] in h (h is dead here)
            transpose_kernel<1><<<dim3(32, NTOK / 32), tb, 0, stream>>>(qb, 2 * CDIM, h, NTOK, CDIM, 3 * CDIM, dflag);
            attn_kernel<<<dim3(BATCH * NH, TSEQ / 64), 256, 0, stream>>>(qb, qb + CDIM, h, ob, 3 * CDIM, NTOK);
            gemm_bt<2><<<dim3(8, 64), 256, 0, stream>>>(ob, WoT, bo, (size_t)l * CDIM, x, nullptr, NTOK, CDIM, CDIM, dflag);
            ln_kernel<0><<<NTOK, 256, 0, stream>>>(x, ln2g, ln2b, (size_t)l * CDIM, h, dflag);
            transpose_kernel<0><<<dim3(128, 32), tb, 0, stream>>>(W1, (size_t)l * CDIM * FFDIM, wT, CDIM, FFDIM, FFDIM, dflag);
            gemm_bt<1><<<dim3(32, 64), 256, 0, stream>>>(h, wT, b1, (size_t)l * FFDIM, nullptr, ffh, NTOK, FFDIM, CDIM, dflag);
            transpose_kernel<0><<<dim3(32, 128), tb, 0, stream>>>(W2, (size_t)l * CDIM * FFDIM, wT, FFDIM, CDIM, CDIM, dflag);
            gemm_bt<2><<<dim3(8, 64), 256, 0, stream>>>(ffh, wT, b2, (size_t)l * CDIM, x, nullptr, NTOK, CDIM, FFDIM, dflag);
        }
        ln_kernel<0><<<NTOK, 256, 0, stream>>>(x, lnfg, lnfb, 0, h, dflag);
        wlmT_kernel<<<wlmT_blocks, 256, 0, stream>>>(Wlm, qb, dflag);   // qb dead after layers
        lmhead2_kernel<<<NTOK / 4, 256, 0, stream>>>(h, qb, blm, d_out, 0, dflag);
    } else if (pool_size >= 34 * MB) {
        // ---------------- Tier B: bf16 residual, chunked ----------------
        int CR, useW2T;
        if      (pool_size >= 52 * MB) { CR = 2048; useW2T = 1; }
        else if (pool_size >= 42 * MB) { CR = 1024; useW2T = 1; }
        else                           { CR = 1024; useW2T = 0; }
        const size_t need = 8 * MB + 16 * MB + (size_t)CR * CDIM * 2 * 5 + (useW2T ? 8 * MB : 0);
        hipMemsetAsync(d_ws, 0, 256 + need, stream);   // defensive full zero
        detect_kernel<<<1, 256, 0, stream>>>(tok, dflag);
        char* p = pool;
        u16* wT = (u16*)p;  p += (size_t)FFDIM * CDIM * 2;   // 8 MB
        u16* WqT = wT;
        u16* WkT = wT + 1 * wsz;
        u16* WvT = wT + 2 * wsz;
        u16* WoT = wT + 3 * wsz;
        u16* xb  = (u16*)p; p += (size_t)NTOK * CDIM * 2;    // 16 MB bf16 residual
        u16* hc  = (u16*)p; p += (size_t)CR * CDIM * 2;      // ln out; VT during attn
        u16* qc  = (u16*)p; p += (size_t)CR * CDIM * 2;      // qc..vc = fused QKV [CR][3072]
        u16* kc  = (u16*)p; p += (size_t)CR * CDIM * 2;      (void)kc;
        u16* vc  = (u16*)p; p += (size_t)CR * CDIM * 2;      (void)vc;
        u16* oc  = (u16*)p; p += (size_t)CR * CDIM * 2;
        u16* ffc = qc;                                       // [CR, FFDIM] aliases q/k/v/o
        u16* W2T = nullptr;
        if (useW2T) { W2T = (u16*)p; p += (size_t)FFDIM * CDIM * 2; }

        embed_kernel<1><<<NTOK * CDIM / 256, 256, 0, stream>>>(idx, tok, pos, xb, dflag);
        for (int l = 0; l < LAYERS; ++l) {
            transpose_kernel<0><<<dim3(32, 32), tb, 0, stream>>>(Wq, l * wsz, WqT, CDIM, CDIM, CDIM, dflag);
            transpose_kernel<0><<<dim3(32, 32), tb, 0, stream>>>(Wk, l * wsz, WkT, CDIM, CDIM, CDIM, dflag);
            transpose_kernel<0><<<dim3(32, 32), tb, 0, stream>>>(Wv, l * wsz, WvT, CDIM, CDIM, CDIM, dflag);
            transpose_kernel<0><<<dim3(32, 32), tb, 0, stream>>>(Wo, l * wsz, WoT, CDIM, CDIM, CDIM, dflag);
            for (int g = 0; g < NTOK / CR; ++g) {
                u16* xg = xb + (size_t)g * CR * CDIM;
                ln_kernel<1><<<CR, 256, 0, stream>>>(xg, ln1g, ln1b, (size_t)l * CDIM, hc, dflag);
                gemm_bt<0><<<dim3(24, CR / 128), 256, 0, stream>>>(hc, wT, nullptr, 0, nullptr, qc, CR, 3 * CDIM, CDIM, dflag);
                transpose_kernel<1><<<dim3(32, CR / 32), tb, 0, stream>>>(qc, 2 * CDIM, hc, CR, CDIM, 3 * CDIM, dflag);
                attn_kernel<<<dim3((CR / TSEQ) * NH, TSEQ / 64), 256, 0, stream>>>(qc, qc + CDIM, hc, oc, 3 * CDIM, CR);
                gemm_bt<3><<<dim3(8, CR / 128), 256, 0, stream>>>(oc, WoT, bo, (size_t)l * CDIM, nullptr, xg, CR, CDIM, CDIM, dflag);
            }
            if (W2T) {
                transpose_kernel<0><<<dim3(128, 32), tb, 0, stream>>>(W1, (size_t)l * CDIM * FFDIM, wT, CDIM, FFDIM, FFDIM, dflag);
                transpose_kernel<0><<<dim3(32, 128), tb, 0, stream>>>(W2, (size_t)l * CDIM * FFDIM, W2T, FFDIM, CDIM, CDIM, dflag);
                for (int g = 0; g < NTOK / CR; ++g) {
                    u16* xg = xb + (size_t)g * CR * CDIM;
                    ln_kernel<1><<<CR, 256, 0, stream>>>(xg, ln2g, ln2b, (size_t)l * CDIM, hc, dflag);
                    gemm_bt<1><<<dim3(32, CR / 128), 256, 0, stream>>>(hc, wT, b1, (size_t)l * FFDIM, nullptr, ffc, CR, FFDIM, CDIM, dflag);
                    gemm_bt<3><<<dim3(8, CR / 128), 256, 0, stream>>>(ffc, W2T, b2, (size_t)l * CDIM, nullptr, xg, CR, CDIM, FFDIM, dflag);
                }
            } else {
                for (int g = 0; g < NTOK / CR; ++g) {
                    u16* xg = xb + (size_t)g * CR * CDIM;
                    ln_kernel<1><<<CR, 256, 0, stream>>>(xg, ln2g, ln2b, (size_t)l * CDIM, hc, dflag);
                    transpose_kernel<0><<<dim3(128, 32), tb, 0, stream>>>(W1, (size_t)l * CDIM * FFDIM, wT, CDIM, FFDIM, FFDIM, dflag);
                    gemm_bt<1><<<dim3(32, CR / 128), 256, 0, stream>>>(hc, wT, b1, (size_t)l * FFDIM, nullptr, ffc, CR, FFDIM, CDIM, dflag);
                    transpose_kernel<0><<<dim3(32, 128), tb, 0, stream>>>(W2, (size_t)l * CDIM * FFDIM, wT, FFDIM, CDIM, CDIM, dflag);
                    gemm_bt<3><<<dim3(8, CR / 128), 256, 0, stream>>>(ffc, wT, b2, (size_t)l * CDIM, nullptr, xg, CR, CDIM, FFDIM, dflag);
                }
            }
        }
        wlmT_kernel<<<wlmT_blocks, 256, 0, stream>>>(Wlm, qc, dflag);   // qc dead after layers
        for (int g = 0; g < NTOK / CR; ++g) {
            u16* xg = xb + (size_t)g * CR * CDIM;
            ln_kernel<1><<<CR, 256, 0, stream>>>(xg, lnfg, lnfb, 0, hc, dflag);
            lmhead2_kernel<<<CR / 4, 256, 0, stream>>>(hc, qc, blm, d_out, (size_t)g * CR * VOCAB, dflag);
        }
    } else {
        // Workspace too small to run at all: emit finite zeros as a diagnostic.
        hipMemsetAsync(d_out, 0, (size_t)out_size * 2, stream);
    }
}

// Round 7
// 2911.161 us; speedup vs baseline: 1.1118x; 1.1118x over previous
//
#include <hip/hip_runtime.h>

typedef unsigned short u16;
typedef unsigned int u32;
typedef __bf16 bf16x8 __attribute__((ext_vector_type(8)));
typedef float f32x4 __attribute__((ext_vector_type(4)));

#define LAYERS 6
#define NH 16
#define CDIM 1024
#define HS 64
#define FFDIM 4096
#define VOCAB 67
#define BATCH 8
#define TSEQ 1024
#define NTOK (BATCH * TSEQ)

__device__ __forceinline__ float bf2f(u16 u) {
    union { u32 i; float f; } x; x.i = ((u32)u) << 16; return x.f;
}
__device__ __forceinline__ u16 f2bf(float f) {  // round-to-nearest-even
    u32 x = __float_as_uint(f);
    u32 r = (x + 0x7fffu + ((x >> 16) & 1u)) >> 16;
    return (u16)r;
}
// dtype-flexible external-input load: f32 ? fp32[i] : bf16[i]
__device__ __forceinline__ float ldx(const void* p, size_t i, int f32) {
    return f32 ? ((const float*)p)[i] : bf2f(((const u16*)p)[i]);
}
// async global->LDS, 16 B per lane; lds base must be wave-uniform (HW scatters +lane*16)
__device__ __forceinline__ void glds16(const u16* g, u16* lds) {
    __builtin_amdgcn_global_load_lds(
        (const __attribute__((address_space(1))) void*)g,
        (__attribute__((address_space(3))) void*)lds, 16, 0, 0);
}

// ---------------------------------------------------------------- dtype detector
__global__ void detect_kernel(const void* __restrict__ tok, int* __restrict__ flag) {
    int bad = 0;
    for (int i = threadIdx.x; i < 4096; i += 256) {
        float f = bf2f(((const u16*)tok)[i]);
        if (!(fabsf(f) < 1000.0f)) bad = 1;   // catches NaN too (comparison false)
    }
    if (bad) atomicOr(flag, 1);
}

// ---------------------------------------------------------------- embedding
template <int BF16OUT>
__global__ void embed_kernel(const int* __restrict__ idx, const void* __restrict__ tok,
                             const void* __restrict__ pos, void* __restrict__ X,
                             const int* __restrict__ dflag) {
    const int f32 = *dflag;
    const int i = blockIdx.x * 256 + threadIdx.x;          // over NTOK*CDIM
    const int n = i >> 10, cc = i & 1023;
    const int t = n & 1023;
    const float v = ldx(tok, (size_t)idx[n] * CDIM + cc, f32) + ldx(pos, (size_t)t * CDIM + cc, f32);
    if constexpr (BF16OUT) ((u16*)X)[i] = f2bf(v);
    else                   ((float*)X)[i] = v;
}

// ---------------------------------------------------------------- transpose
// src rows r (0..R-1) with row stride SC at column offset inside soff; C cols moved.
// dst[c*R + r] (bf16). BF16SRC=1 forces bf16 source (internal buffers).
template <int BF16SRC>
__global__ void transpose_kernel(const void* __restrict__ src, size_t soff, u16* __restrict__ dst,
                                 int R, int C, int SC, const int* __restrict__ dflag) {
    __shared__ u16 tile[32][33];
    const int f32 = BF16SRC ? 0 : *dflag;
    const int bx = blockIdx.x * 32, by = blockIdx.y * 32;
    const int tx = threadIdx.x, ty = threadIdx.y;          // block (32,8)
    #pragma unroll
    for (int i = 0; i < 32; i += 8) {
        const size_t si = soff + (size_t)(by + ty + i) * SC + bx + tx;
        tile[ty + i][tx] = f32 ? f2bf(((const float*)src)[si]) : ((const u16*)src)[si];
    }
    __syncthreads();
    #pragma unroll
    for (int i = 0; i < 32; i += 8) dst[(size_t)(bx + ty + i) * R + by + tx] = tile[tx][ty + i];
}

// ---------------------------------------------------------------- layernorm (two-pass), fp32 or bf16 input row
template <int BF16IN>
__global__ __launch_bounds__(256) void ln_kernel(const void* __restrict__ Xv, const void* __restrict__ g,
                                                 const void* __restrict__ b, size_t loff,
                                                 u16* __restrict__ Hout, const int* __restrict__ dflag) {
    __shared__ float sred[4];
    const int f32 = *dflag;
    const int row = blockIdx.x, tid = threadIdx.x;
    float v[4];
    if constexpr (BF16IN) {
        const u16* xr = (const u16*)Xv + (size_t)row * CDIM;
        #pragma unroll
        for (int i = 0; i < 4; ++i) v[i] = bf2f(xr[tid + i * 256]);
    } else {
        const float* xr = (const float*)Xv + (size_t)row * CDIM;
        #pragma unroll
        for (int i = 0; i < 4; ++i) v[i] = xr[tid + i * 256];
    }
    float s = v[0] + v[1] + v[2] + v[3];
    #pragma unroll
    for (int off = 1; off < 64; off <<= 1) s += __shfl_xor(s, off, 64);
    if ((tid & 63) == 0) sred[tid >> 6] = s;
    __syncthreads();
    const float mean = (sred[0] + sred[1] + sred[2] + sred[3]) * (1.f / 1024.f);
    __syncthreads();
    float sq = 0.f;
    #pragma unroll
    for (int i = 0; i < 4; ++i) { v[i] -= mean; sq += v[i] * v[i]; }
    #pragma unroll
    for (int off = 1; off < 64; off <<= 1) sq += __shfl_xor(sq, off, 64);
    if ((tid & 63) == 0) sred[tid >> 6] = sq;
    __syncthreads();
    const float var = (sred[0] + sred[1] + sred[2] + sred[3]) * (1.f / 1024.f);
    const float inv = rsqrtf(var + 1e-5f);
    u16* hr = Hout + (size_t)row * CDIM;
    #pragma unroll
    for (int i = 0; i < 4; ++i) {
        const int cc = tid + i * 256;
        hr[cc] = f2bf(v[i] * inv * ldx(g, loff + cc, f32) + ldx(b, loff + cc, f32));
    }
}

// ---------------------------------------------------------------- GEMM  C[M,N] = A[M,K] @ BT[N,K]^T
// MODE 0: Out=bf16(acc);  MODE 1: Out=bf16(relu(acc+bias));
// MODE 2: X(fp32) += acc+bias;  MODE 3: Out(bf16) = bf16(bf2f(Out)+acc+bias)
// global_load_lds staging with XOR-swizzled LDS (linear dest + inverse-permuted
// source + permuted read). XCD strip mapping, bx-inner for A-panel L2 reuse.
template <int MODE>
__global__ __launch_bounds__(256) void gemm_bt(const u16* __restrict__ A, const u16* __restrict__ BT,
                                               const void* __restrict__ bias, size_t boff,
                                               float* __restrict__ X, u16* __restrict__ Out,
                                               int M, int N, int K, const int* __restrict__ dflag) {
    __shared__ u16 As[128][64];
    __shared__ u16 Bs[128][64];
    const int tid = threadIdx.x;
    const int lane = tid & 63;
    const int w = tid >> 6;
    const int wr = w >> 1, wc = w & 1;
    const int quad = lane >> 4, c = lane & 15;

    const int gx = gridDim.x, gy = gridDim.y;
    int bx = blockIdx.x, by = blockIdx.y;
    const int nwg = gx * gy;
    if ((nwg & 7) == 0) {
        const int bid = by * gx + bx;
        const int q = nwg >> 3;
        const int xcd = bid & 7;
        const int u = bid >> 3;             // local index within this XCD's strip
        const int cols = q / gy;
        if (cols * gy == q) {               // exact strip: cols consecutive bx columns
            bx = xcd * cols + (u % cols);   // bx-inner: A-panel (by) reused across cols
            by = u / cols;
        } else {                            // fallback: contiguous column-major strip
            const int l = xcd * q + u;
            bx = l / gy;
            by = l - bx * gy;
        }
    }
    const int m0 = by * 128, n0 = bx * 128;

    const int lr = lane >> 3;              // row-within-8 per lane
    const int sc = ((lane & 7) ^ lr) * 8;  // inverse-swizzled source chunk (u16 units)

    const f32x4 zero4 = {0.f, 0.f, 0.f, 0.f};
    f32x4 acc[4][4];
    #pragma unroll
    for (int i = 0; i < 4; ++i)
        #pragma unroll
        for (int j = 0; j < 4; ++j) acc[i][j] = zero4;

    for (int k0 = 0; k0 < K; k0 += 64) {
        #pragma unroll
        for (int i = 0; i < 4; ++i) {
            const int rbase = w * 8 + i * 32;   // wave-uniform LDS row base (mult of 8)
            glds16(A  + (size_t)(m0 + rbase + lr) * K + k0 + sc, &As[rbase][0]);
            glds16(BT + (size_t)(n0 + rbase + lr) * K + k0 + sc, &Bs[rbase][0]);
        }
        __syncthreads();   // compiler drains vmcnt(0) before s_barrier
        #pragma unroll
        for (int ks = 0; ks < 2; ++ks) {
            bf16x8 af[4], bfr[4];
            #pragma unroll
            for (int t = 0; t < 4; ++t) {
                const int ch = ((ks * 4 + quad) ^ (c & 7)) * 8;   // swizzled read chunk
                af[t]  = *(const bf16x8*)(&As[wr * 64 + t * 16 + c][ch]);
                bfr[t] = *(const bf16x8*)(&Bs[wc * 64 + t * 16 + c][ch]);
            }
            #pragma unroll
            for (int mt = 0; mt < 4; ++mt)
                #pragma unroll
                for (int nt = 0; nt < 4; ++nt)
                    acc[mt][nt] = __builtin_amdgcn_mfma_f32_16x16x32_bf16(af[mt], bfr[nt], acc[mt][nt], 0, 0, 0);
        }
        __syncthreads();
    }

    int f32 = 0;
    if constexpr (MODE >= 1) f32 = *dflag;
    #pragma unroll
    for (int mt = 0; mt < 4; ++mt) {
        #pragma unroll
        for (int nt = 0; nt < 4; ++nt) {
            const int col = n0 + wc * 64 + nt * 16 + c;
            float bv = 0.f;
            if constexpr (MODE >= 1) bv = ldx(bias, boff + col, f32);
            #pragma unroll
            for (int r = 0; r < 4; ++r) {
                const size_t row = (size_t)(m0 + wr * 64 + mt * 16 + quad * 4 + r);
                float v = acc[mt][nt][r];
                if constexpr (MODE == 2) {
                    X[row * N + col] += v + bv;
                } else if constexpr (MODE == 3) {
                    u16* o = &Out[row * N + col];
                    *o = f2bf(bf2f(*o) + v + bv);
                } else if constexpr (MODE == 1) {
                    v += bv; v = fmaxf(v, 0.f);
                    Out[row * N + col] = f2bf(v);
                } else {
                    Out[row * N + col] = f2bf(v);
                }
            }
        }
    }
}

// ---------------------------------------------------------------- flash attention v3 (causal, H=16, HS=64)
// K and V^T tiles staged in LDS via global_load_lds with XOR swizzle (conflict-free
// reads); Q direct from global (read once); P per-wave in LDS, swizzled, no barrier.
// rs = Q/K row stride (3072 fused); VT = pre-transposed V [CDIM][vstride tokens].
// Block remap: each XCD owns 1/8 of (b,h); longest q-blocks dispatch first.
__global__ __launch_bounds__(256) void attn_kernel(const u16* __restrict__ Qb, const u16* __restrict__ Kb,
                                                   const u16* __restrict__ VT, u16* __restrict__ Ob,
                                                   int rs, int vstride) {
    __shared__ u16 Ks[64][64];       // K rows, swizzled: LDS[r][ch] = K[r][ch^(r&7)]
    __shared__ u16 Vts[64][64];      // V^T rows (d), swizzled likewise
    __shared__ u16 Ps[4][16][64];    // per-wave P tile (q x k), XOR-swizzled

    const int tid = threadIdx.x;
    const int lane = tid & 63;
    const int w = tid >> 6;
    const int quad = lane >> 4;
    const int c = lane & 15;

    const int nbh = gridDim.x, nq = gridDim.y;
    int bh, qi;
    {
        const int flat = blockIdx.y * nbh + blockIdx.x;
        if ((nbh & 7) == 0) {
            const int bpx = nbh >> 3;           // bh per XCD
            const int xcd = flat & 7;
            const int u = flat >> 3;
            bh = xcd * bpx + (u % bpx);
            qi = nq - 1 - u / bpx;              // longest-first
        } else { bh = blockIdx.x; qi = blockIdx.y; }
    }
    const int b = bh >> 4;
    const int h = bh & 15;
    const int q0 = qi * 64;
    const size_t base = ((size_t)b * TSEQ) * rs + (size_t)h * HS;

    const int qbase = q0 + w * 16;
    const u16* qrow = Qb + base + (size_t)(qbase + c) * rs;
    const bf16x8 qf0 = *(const bf16x8*)(qrow + quad * 8);
    const bf16x8 qf1 = *(const bf16x8*)(qrow + 32 + quad * 8);

    const u16* vsrc = VT + (size_t)(h * HS) * vstride + (size_t)b * TSEQ;

    const int lr = lane >> 3;              // row-within-8 per lane (staging)
    const int sc = ((lane & 7) ^ lr) * 8;  // inverse-swizzled source chunk

    const f32x4 zero4 = {0.f, 0.f, 0.f, 0.f};
    f32x4 oacc[4] = {zero4, zero4, zero4, zero4};
    float m_r[4], l_r[4];
    #pragma unroll
    for (int r = 0; r < 4; ++r) { m_r[r] = -1e30f; l_r[r] = 0.f; }

    const int nch = qi + 1;   // causal: keys up to q0+63
    for (int ch = 0; ch < nch; ++ch) {
        const int k0 = ch * 64;
        {   // stage K tile and V^T tile: each wave 2 issues x 8 rows each
            const int rbase = w * 16;
            glds16(Kb + base + (size_t)(k0 + rbase + lr) * rs + sc,      &Ks[rbase][0]);
            glds16(Kb + base + (size_t)(k0 + rbase + 8 + lr) * rs + sc,  &Ks[rbase + 8][0]);
            glds16(vsrc + (size_t)(rbase + lr) * vstride + k0 + sc,      &Vts[rbase][0]);
            glds16(vsrc + (size_t)(rbase + 8 + lr) * vstride + k0 + sc,  &Vts[rbase + 8][0]);
        }
        __syncthreads();   // drains vmcnt(0)

        f32x4 s[4];
        #pragma unroll
        for (int kt = 0; kt < 4; ++kt) {
            const int krow = kt * 16 + c;
            const bf16x8 kf0 = *(const bf16x8*)(&Ks[krow][((quad) ^ (c & 7)) * 8]);
            const bf16x8 kf1 = *(const bf16x8*)(&Ks[krow][((4 + quad) ^ (c & 7)) * 8]);
            f32x4 t0 = __builtin_amdgcn_mfma_f32_16x16x32_bf16(qf0, kf0, zero4, 0, 0, 0);
            s[kt] = __builtin_amdgcn_mfma_f32_16x16x32_bf16(qf1, kf1, t0, 0, 0, 0);
        }
        #pragma unroll
        for (int kt = 0; kt < 4; ++kt) {
            const int kabs = k0 + kt * 16 + c;
            #pragma unroll
            for (int r = 0; r < 4; ++r) {
                s[kt][r] *= 0.125f;    // 1/sqrt(HS), exact
                if (kabs > qbase + quad * 4 + r) s[kt][r] = -1e30f;
            }
        }
        float p[4][4];
        #pragma unroll
        for (int r = 0; r < 4; ++r) {
            float rm = fmaxf(fmaxf(s[0][r], s[1][r]), fmaxf(s[2][r], s[3][r]));
            #pragma unroll
            for (int off = 1; off < 16; off <<= 1) rm = fmaxf(rm, __shfl_xor(rm, off, 16));
            const float mnew = fmaxf(m_r[r], rm);
            const float alpha = __expf(m_r[r] - mnew);
            float psum = 0.f;
            #pragma unroll
            for (int kt = 0; kt < 4; ++kt) {
                const float e = __expf(s[kt][r] - mnew);
                p[kt][r] = e; psum += e;
            }
            #pragma unroll
            for (int off = 1; off < 16; off <<= 1) psum += __shfl_xor(psum, off, 16);
            l_r[r] = l_r[r] * alpha + psum;
            m_r[r] = mnew;
            #pragma unroll
            for (int dt = 0; dt < 4; ++dt) oacc[dt][r] *= alpha;
        }
        // write P swizzled: LDS chunk = (G-chunk) ^ (row&7); per-wave tile -> no barrier
        #pragma unroll
        for (int kt = 0; kt < 4; ++kt)
            #pragma unroll
            for (int r = 0; r < 4; ++r) {
                const int prow = quad * 4 + r;
                const int ch2 = (kt * 2 + (c >> 3)) ^ (prow & 7);
                Ps[w][prow][ch2 * 8 + (c & 7)] = f2bf(p[kt][r]);
            }
        #pragma unroll
        for (int ks2 = 0; ks2 < 2; ++ks2) {
            const bf16x8 pf = *(const bf16x8*)(&Ps[w][c][(((ks2 * 4 + quad) ^ (c & 7))) * 8]);
            #pragma unroll
            for (int dt = 0; dt < 4; ++dt) {
                const int vrow = dt * 16 + c;
                const bf16x8 vf = *(const bf16x8*)(&Vts[vrow][((ks2 * 4 + quad) ^ (c & 7)) * 8]);
                oacc[dt] = __builtin_amdgcn_mfma_f32_16x16x32_bf16(pf, vf, oacc[dt], 0, 0, 0);
            }
        }
        __syncthreads();   // all waves done reading Ks/Vts before next stage
    }
    #pragma unroll
    for (int dt = 0; dt < 4; ++dt)
        #pragma unroll
        for (int r = 0; r < 4; ++r) {
            const size_t row = (size_t)b * TSEQ + qbase + quad * 4 + r;
            Ob[row * CDIM + h * HS + dt * 16 + c] = f2bf(oacc[dt][r] / l_r[r]);
        }
}

// ---------------------------------------------------------------- Wlm transpose: Wlm[C,V] -> WlmT[V][C] bf16
__global__ void wlmT_kernel(const void* __restrict__ Wlm, u16* __restrict__ WlmT,
                            const int* __restrict__ dflag) {
    const int f32 = *dflag;
    const int i = blockIdx.x * 256 + threadIdx.x;   // over VOCAB*CDIM
    if (i >= VOCAB * CDIM) return;
    const int v = i >> 10, cc = i & 1023;
    WlmT[i] = f2bf(ldx(Wlm, (size_t)cc * VOCAB + v, f32));
}

// ---------------------------------------------------------------- LM head v2: one wave per token row
__device__ __forceinline__ void ld16bf(const u16* p, float* v) {
    const uint4 a = *(const uint4*)(p);
    const uint4 b = *(const uint4*)(p + 8);
    u32 t[8] = {a.x, a.y, a.z, a.w, b.x, b.y, b.z, b.w};
    #pragma unroll
    for (int i = 0; i < 8; ++i) {
        v[2 * i]     = bf2f((u16)(t[i] & 0xffffu));
        v[2 * i + 1] = bf2f((u16)(t[i] >> 16));
    }
}

__global__ __launch_bounds__(256) void lmhead2_kernel(const u16* __restrict__ Hf, const u16* __restrict__ WlmT,
                                                      const void* __restrict__ blm, void* __restrict__ out,
                                                      size_t ooff, const int* __restrict__ dflag) {
    const int f32 = *dflag;
    const int lane = threadIdx.x & 63;
    const int n = blockIdx.x * 4 + (threadIdx.x >> 6);     // 4 waves per block, 1 row per wave
    float hv[16];
    ld16bf(Hf + (size_t)n * CDIM + lane * 16, hv);
    for (int v = 0; v < VOCAB; ++v) {
        float wv[16];
        ld16bf(WlmT + (size_t)v * CDIM + lane * 16, wv);
        float s = 0.f;
        #pragma unroll
        for (int i = 0; i < 16; ++i) s += hv[i] * wv[i];
        #pragma unroll
        for (int off = 1; off < 64; off <<= 1) s += __shfl_xor(s, off, 64);
        if (lane == 0) {
            s += ldx(blm, v, f32);
            const size_t o = ooff + (size_t)n * VOCAB + v;
            if (f32) ((float*)out)[o] = s;
            else     ((u16*)out)[o]   = f2bf(s);
        }
    }
}

// ---------------------------------------------------------------- launcher
extern "C" void kernel_launch(void* const* d_in, const int* in_sizes, int n_in,
                              void* d_out, int out_size, void* d_ws, size_t ws_size,
                              hipStream_t stream) {
    const int*  idx  = (const int*)d_in[0];
    const void* tok  = d_in[1];
    const void* pos  = d_in[2];
    const void* Wq   = d_in[3];
    const void* Wk   = d_in[4];
    const void* Wv   = d_in[5];
    const void* Wo   = d_in[6];
    const void* bo   = d_in[7];
    const void* ln1g = d_in[8];
    const void* ln1b = d_in[9];
    const void* ln2g = d_in[10];
    const void* ln2b = d_in[11];
    const void* W1   = d_in[12];
    const void* b1   = d_in[13];
    const void* W2   = d_in[14];
    const void* b2   = d_in[15];
    const void* lnfg = d_in[16];
    const void* lnfb = d_in[17];
    const void* Wlm  = d_in[18];
    const void* blm  = d_in[19];

    const dim3 tb(32, 8);
    const size_t wsz = (size_t)CDIM * CDIM;
    const size_t MB = 1048576ull;

    int* dflag = (int*)d_ws;                    // flag at ws[0..4); pool after 256 B
    char* pool = (char*)d_ws + 256;
    const size_t pool_size = (ws_size > 256) ? ws_size - 256 : 0;

    const int wlmT_blocks = (VOCAB * CDIM + 255) / 256;

    if (pool_size >= 120 * MB) {
        // ---------------- Tier A: full-size activations, fp32 residual ----------------
        hipMemsetAsync(d_ws, 0, 256 + 120 * MB, stream);   // defensive full-pool zero
        detect_kernel<<<1, 256, 0, stream>>>(tok, dflag);
        char* p = pool;
        u16* wT = (u16*)p;  p += (size_t)FFDIM * CDIM * 2;   // 8 MB
        u16* WqT = wT;
        u16* WkT = wT + 1 * wsz;
        u16* WvT = wT + 2 * wsz;
        u16* WoT = wT + 3 * wsz;
        float* x = (float*)p; p += (size_t)NTOK * CDIM * 4;  // 32 MB
        u16* h   = (u16*)p;   p += (size_t)NTOK * CDIM * 2;  // 16 MB (also VT during attn)
        u16* qb  = (u16*)p;   p += (size_t)NTOK * CDIM * 2;  // qb..vb = fused QKV [NTOK][3072]
        u16* kb  = (u16*)p;   p += (size_t)NTOK * CDIM * 2;  (void)kb;
        u16* vb  = (u16*)p;   p += (size_t)NTOK * CDIM * 2;  (void)vb;
        u16* ob  = (u16*)p;   p += (size_t)NTOK * CDIM * 2;
        u16* ffh = qb;

        embed_kernel<0><<<NTOK * CDIM / 256, 256, 0, stream>>>(idx, tok, pos, x, dflag);
        for (int l = 0; l < LAYERS; ++l) {
            transpose_kernel<0><<<dim3(32, 32), tb, 0, stream>>>(Wq, l * wsz, WqT, CDIM, CDIM, CDIM, dflag);
            transpose_kernel<0><<<dim3(32, 32), tb, 0, stream>>>(Wk, l * wsz, WkT, CDIM, CDIM, CDIM, dflag);
            transpose_kernel<0><<<dim3(32, 32), tb, 0, stream>>>(Wv, l * wsz, WvT, CDIM, CDIM, CDIM, dflag);
            transpose_kernel<0><<<dim3(32, 32), tb, 0, stream>>>(Wo, l * wsz, WoT, CDIM, CDIM, CDIM, dflag);
            ln_kernel<0><<<NTOK, 256, 0, stream>>>(x, ln1g, ln1b, (size_t)l * CDIM, h, dflag);
            // fused QKV: BT = stacked [WqT;WkT;WvT], out row stride 3072
            gemm_bt<0><<<dim3(24, 64), 256, 0, stream>>>(h, wT, nullptr, 0, nullptr, qb, NTOK, 3 * CDIM, CDIM, dflag);
            // V columns of fused buffer -> VT[CDIM][NTOK] in h (h is dead here)
            transpose_kernel<1><<<dim3(32, NTOK / 32), tb, 0, stream>>>(qb, 2 * CDIM, h, NTOK, CDIM, 3 * CDIM, dflag);
            attn_kernel<<<dim3(BATCH * NH, TSEQ / 64), 256, 0, stream>>>(qb, qb + CDIM, h, ob, 3 * CDIM, NTOK);
            gemm_bt<2><<<dim3(8, 64), 256, 0, stream>>>(ob, WoT, bo, (size_t)l * CDIM, x, nullptr, NTOK, CDIM, CDIM, dflag);
            ln_kernel<0><<<NTOK, 256, 0, stream>>>(x, ln2g, ln2b, (size_t)l * CDIM, h, dflag);
            transpose_kernel<0><<<dim3(128, 32), tb, 0, stream>>>(W1, (size_t)l * CDIM * FFDIM, wT, CDIM, FFDIM, FFDIM, dflag);
            gemm_bt<1><<<dim3(32, 64), 256, 0, stream>>>(h, wT, b1, (size_t)l * FFDIM, nullptr, ffh, NTOK, FFDIM, CDIM, dflag);
            transpose_kernel<0><<<dim3(32, 128), tb, 0, stream>>>(W2, (size_t)l * CDIM * FFDIM, wT, FFDIM, CDIM, CDIM, dflag);
            gemm_bt<2><<<dim3(8, 64), 256, 0, stream>>>(ffh, wT, b2, (size_t)l * CDIM, x, nullptr, NTOK, CDIM, FFDIM, dflag);
        }
        ln_kernel<0><<<NTOK, 256, 0, stream>>>(x, lnfg, lnfb, 0, h, dflag);
        wlmT_kernel<<<wlmT_blocks, 256, 0, stream>>>(Wlm, qb, dflag);   // qb dead after layers
        lmhead2_kernel<<<NTOK / 4, 256, 0, stream>>>(h, qb, blm, d_out, 0, dflag);
    } else if (pool_size >= 34 * MB) {
        // ---------------- Tier B: bf16 residual, chunked ----------------
        int CR, useW2T;
        if      (pool_size >= 52 * MB) { CR = 2048; useW2T = 1; }
        else if (pool_size >= 42 * MB) { CR = 1024; useW2T = 1; }
        else                           { CR = 1024; useW2T = 0; }
        const size_t need = 8 * MB + 16 * MB + (size_t)CR * CDIM * 2 * 5 + (useW2T ? 8 * MB : 0);
        hipMemsetAsync(d_ws, 0, 256 + need, stream);   // defensive full zero
        detect_kernel<<<1, 256, 0, stream>>>(tok, dflag);
        char* p = pool;
        u16* wT = (u16*)p;  p += (size_t)FFDIM * CDIM * 2;   // 8 MB
        u16* WqT = wT;
        u16* WkT = wT + 1 * wsz;
        u16* WvT = wT + 2 * wsz;
        u16* WoT = wT + 3 * wsz;
        u16* xb  = (u16*)p; p += (size_t)NTOK * CDIM * 2;    // 16 MB bf16 residual
        u16* hc  = (u16*)p; p += (size_t)CR * CDIM * 2;      // ln out; VT during attn
        u16* qc  = (u16*)p; p += (size_t)CR * CDIM * 2;      // qc..vc = fused QKV [CR][3072]
        u16* kc  = (u16*)p; p += (size_t)CR * CDIM * 2;      (void)kc;
        u16* vc  = (u16*)p; p += (size_t)CR * CDIM * 2;      (void)vc;
        u16* oc  = (u16*)p; p += (size_t)CR * CDIM * 2;
        u16* ffc = qc;                                       // [CR, FFDIM] aliases q/k/v/o
        u16* W2T = nullptr;
        if (useW2T) { W2T = (u16*)p; p += (size_t)FFDIM * CDIM * 2; }

        embed_kernel<1><<<NTOK * CDIM / 256, 256, 0, stream>>>(idx, tok, pos, xb, dflag);
        for (int l = 0; l < LAYERS; ++l) {
            transpose_kernel<0><<<dim3(32, 32), tb, 0, stream>>>(Wq, l * wsz, WqT, CDIM, CDIM, CDIM, dflag);
            transpose_kernel<0><<<dim3(32, 32), tb, 0, stream>>>(Wk, l * wsz, WkT, CDIM, CDIM, CDIM, dflag);
            transpose_kernel<0><<<dim3(32, 32), tb, 0, stream>>>(Wv, l * wsz, WvT, CDIM, CDIM, CDIM, dflag);
            transpose_kernel<0><<<dim3(32, 32), tb, 0, stream>>>(Wo, l * wsz, WoT, CDIM, CDIM, CDIM, dflag);
            for (int g = 0; g < NTOK / CR; ++g) {
                u16* xg = xb + (size_t)g * CR * CDIM;
                ln_kernel<1><<<CR, 256, 0, stream>>>(xg, ln1g, ln1b, (size_t)l * CDIM, hc, dflag);
                gemm_bt<0><<<dim3(24, CR / 128), 256, 0, stream>>>(hc, wT, nullptr, 0, nullptr, qc, CR, 3 * CDIM, CDIM, dflag);
                transpose_kernel<1><<<dim3(32, CR / 32), tb, 0, stream>>>(qc, 2 * CDIM, hc, CR, CDIM, 3 * CDIM, dflag);
                attn_kernel<<<dim3((CR / TSEQ) * NH, TSEQ / 64), 256, 0, stream>>>(qc, qc + CDIM, hc, oc, 3 * CDIM, CR);
                gemm_bt<3><<<dim3(8, CR / 128), 256, 0, stream>>>(oc, WoT, bo, (size_t)l * CDIM, nullptr, xg, CR, CDIM, CDIM, dflag);
            }
            if (W2T) {
                transpose_kernel<0><<<dim3(128, 32), tb, 0, stream>>>(W1, (size_t)l * CDIM * FFDIM, wT, CDIM, FFDIM, FFDIM, dflag);
                transpose_kernel<0><<<dim3(32, 128), tb, 0, stream>>>(W2, (size_t)l * CDIM * FFDIM, W2T, FFDIM, CDIM, CDIM, dflag);
                for (int g = 0; g < NTOK / CR; ++g) {
                    u16* xg = xb + (size_t)g * CR * CDIM;
                    ln_kernel<1><<<CR, 256, 0, stream>>>(xg, ln2g, ln2b, (size_t)l * CDIM, hc, dflag);
                    gemm_bt<1><<<dim3(32, CR / 128), 256, 0, stream>>>(hc, wT, b1, (size_t)l * FFDIM, nullptr, ffc, CR, FFDIM, CDIM, dflag);
                    gemm_bt<3><<<dim3(8, CR / 128), 256, 0, stream>>>(ffc, W2T, b2, (size_t)l * CDIM, nullptr, xg, CR, CDIM, FFDIM, dflag);
                }
            } else {
                for (int g = 0; g < NTOK / CR; ++g) {
                    u16* xg = xb + (size_t)g * CR * CDIM;
                    ln_kernel<1><<<CR, 256, 0, stream>>>(xg, ln2g, ln2b, (size_t)l * CDIM, hc, dflag);
                    transpose_kernel<0><<<dim3(128, 32), tb, 0, stream>>>(W1, (size_t)l * CDIM * FFDIM, wT, CDIM, FFDIM, FFDIM, dflag);
                    gemm_bt<1><<<dim3(32, CR / 128), 256, 0, stream>>>(hc, wT, b1, (size_t)l * FFDIM, nullptr, ffc, CR, FFDIM, CDIM, dflag);
                    transpose_kernel<0><<<dim3(32, 128), tb, 0, stream>>>(W2, (size_t)l * CDIM * FFDIM, wT, FFDIM, CDIM, CDIM, dflag);
                    gemm_bt<3><<<dim3(8, CR / 128), 256, 0, stream>>>(ffc, wT, b2, (size_t)l * CDIM, nullptr, xg, CR, CDIM, FFDIM, dflag);
                }
            }
        }
        wlmT_kernel<<<wlmT_blocks, 256, 0, stream>>>(Wlm, qc, dflag);   // qc dead after layers
        for (int g = 0; g < NTOK / CR; ++g) {
            u16* xg = xb + (size_t)g * CR * CDIM;
            ln_kernel<1><<<CR, 256, 0, stream>>>(xg, lnfg, lnfb, 0, hc, dflag);
            lmhead2_kernel<<<CR / 4, 256, 0, stream>>>(hc, qc, blm, d_out, (size_t)g * CR * VOCAB, dflag);
        }
    } else {
        // Workspace too small to run at all: emit finite zeros as a diagnostic.
        hipMemsetAsync(d_out, 0, (size_t)out_size * 2, stream);
    }
}